// Round 5
// baseline (1114.649 us; speedup 1.0000x reference)
//
#include <hip/hip_runtime.h>
#include <hip/hip_bf16.h>

// ---- problem geometry ----
#define NROWS   131072          // 32*4096
#define DIM     64
#define NEMB    512
// output offsets (floats)
#define OUT_Q     0
#define OUT_DIFF  8388608
#define OUT_IND   8388609
#define OUT_OH    8519681      // 8388609 + 131072
#define OUT_ES    8520193      // OUT_OH + 512
// ws layout (floats)
#define WS_EN     0
#define WS_ET     512           // embedT [512][64]
#define WS_KEY    33280         // u64 keys [131072], 8B-aligned
#define WS_HIST   295424        // u32[512]
#define WS_START  295936        // u32[512]
#define WS_CURS   296448        // u32[512]
#define WS_BUCKET 296960        // u32[131072]
#define WS_NEED   428032        // floats for the sort path
#define WS_PART   295424        // fallback: P partial embed_sum copies
#define NCHUNK    4
#define CODES_PER_CHUNK 128

__global__ __launch_bounds__(256) void vq_prep(const float* __restrict__ embed,
                                               float* __restrict__ ws,
                                               float* __restrict__ out,
                                               int P, int mode) {  // mode: 2=sort,1=keys+part,0=mono
  const int tid = blockIdx.x * 256 + threadIdx.x;
  const int nth = gridDim.x * 256;
  for (int e = tid; e < NEMB * DIM; e += nth) {          // embedT[j][d]
    int j = e >> 6, d = e & 63;
    ws[WS_ET + e] = embed[d * NEMB + j];
  }
  for (int j = tid; j < NEMB; j += nth) {                // en[j]
    float s = 0.f;
    for (int d = 0; d < DIM; ++d) {
      float v = embed[d * NEMB + j];
      s = fmaf(v, v, s);
    }
    ws[WS_EN + j] = s;
  }
  if (tid == 0) out[OUT_DIFF] = 0.f;
  if (mode >= 1) {
    unsigned long long* keys = reinterpret_cast<unsigned long long*>(ws + WS_KEY);
    for (int r = tid; r < NROWS; r += nth) keys[r] = ~0ULL;
  }
  if (mode == 2) {
    unsigned* hist = reinterpret_cast<unsigned*>(ws + WS_HIST);
    for (int k = tid; k < NEMB; k += nth) hist[k] = 0u;
  } else {
    // fallback paths accumulate onehot/embed_sum atomically -> need zeros
    for (int e = tid; e < NEMB + NEMB * DIM; e += nth) out[OUT_OH + e] = 0.f;
    for (long e = tid; e < (long)P * (NEMB * DIM); e += nth) ws[WS_PART + e] = 0.f;
  }
}

// Distance + per-chunk argmin (unchanged from round 4).
__global__ __launch_bounds__(256, 4) void vq_dist(
    const float* __restrict__ input, const float* __restrict__ embed,
    const float* __restrict__ ws, unsigned long long* __restrict__ keys) {
  const int i = blockIdx.x * 256 + threadIdx.x;
  const int jbase = blockIdx.y * CODES_PER_CHUNK;

  float x[DIM];
  const float4* xin = reinterpret_cast<const float4*>(input + (size_t)i * DIM);
#pragma unroll
  for (int k = 0; k < 16; ++k) {
    float4 v = xin[k];
    x[4 * k + 0] = v.x; x[4 * k + 1] = v.y; x[4 * k + 2] = v.z; x[4 * k + 3] = v.w;
  }
  float xx = 0.f;
#pragma unroll
  for (int d = 0; d < DIM; ++d) xx = fmaf(x[d], x[d], xx);

  float best = 3.4e38f;
  int   bj   = jbase;
#pragma unroll 1
  for (int jt2 = 0; jt2 < CODES_PER_CHUNK; jt2 += 8) {
    const int jt = jbase + jt2;
    float acc[8];
#pragma unroll
    for (int u = 0; u < 8; ++u) acc[u] = 0.f;
#pragma unroll
    for (int d = 0; d < DIM; ++d) {
      const float xv = x[d];
#pragma unroll
      for (int u = 0; u < 8; ++u)
        acc[u] = fmaf(xv, embed[d * NEMB + jt + u], acc[u]);
    }
#pragma unroll
    for (int u = 0; u < 8; ++u) {
      float dist = (xx - 2.0f * acc[u]) + ws[WS_EN + jt + u];
      if (dist < best) { best = dist; bj = jt + u; }
    }
  }
  const unsigned long long key =
      ((unsigned long long)__float_as_uint(fmaxf(best, 0.0f)) << 32) |
      (unsigned long long)(unsigned)bj;
  atomicMin(keys + i, key);
}

// ---- sort path ----
__global__ __launch_bounds__(256) void vq_hist(
    const unsigned long long* __restrict__ keys, unsigned* __restrict__ hist) {
  __shared__ unsigned lh[NEMB];
  const int tid = threadIdx.x;
  for (int k = tid; k < NEMB; k += 256) lh[k] = 0u;
  __syncthreads();
  for (int i = blockIdx.x * 256 + tid; i < NROWS; i += gridDim.x * 256)
    atomicAdd(&lh[(unsigned)(keys[i] & 0xffffffffULL)], 1u);
  __syncthreads();
  for (int k = tid; k < NEMB; k += 256)
    if (lh[k]) atomicAdd(hist + k, lh[k]);
}

__global__ __launch_bounds__(512) void vq_scan(
    const unsigned* __restrict__ hist, unsigned* __restrict__ start,
    unsigned* __restrict__ curs, float* __restrict__ out) {
  __shared__ unsigned lsum[8];
  const int tid = threadIdx.x, lane = tid & 63, wid = tid >> 6;
  unsigned h = hist[tid];
  unsigned v = h;
#pragma unroll
  for (int s = 1; s < 64; s <<= 1) {
    unsigned t = (unsigned)__shfl_up((int)v, s, 64);
    if (lane >= s) v += t;
  }
  if (lane == 63) lsum[wid] = v;
  __syncthreads();
  if (tid == 0) {
    unsigned run = 0;
#pragma unroll
    for (int w = 0; w < 8; ++w) { unsigned t = lsum[w]; lsum[w] = run; run += t; }
  }
  __syncthreads();
  const unsigned excl = v - h + lsum[wid];
  start[tid] = excl;
  curs[tid]  = excl;
  out[OUT_OH + tid] = (float)h;
}

__global__ __launch_bounds__(256) void vq_scatter(
    const unsigned long long* __restrict__ keys, unsigned* __restrict__ curs,
    unsigned* __restrict__ bucket) {
  const int i = blockIdx.x * 256 + threadIdx.x;
  const unsigned J = (unsigned)(keys[i] & 0xffffffffULL);
  const unsigned pos = atomicAdd(curs + J, 1u);
  bucket[pos] = (unsigned)i;
}

// One block per code: sum rows (no atomics), write quantize/ind/embed_sum/diff.
__global__ __launch_bounds__(256) void vq_finsum(
    const float* __restrict__ input, const float* __restrict__ ws,
    const unsigned* __restrict__ start, const unsigned* __restrict__ hist,
    const unsigned* __restrict__ bucket, float* __restrict__ out) {
  __shared__ float sacc[4][64];
  __shared__ float dred[4];
  const int j    = blockIdx.x;
  const int tid  = threadIdx.x;
  const int lane = tid & 63;
  const int wid  = tid >> 6;
  const unsigned s0  = start[j];
  const unsigned cnt = hist[j];
  const float q = ws[WS_ET + (size_t)j * DIM + lane];   // codebook row, lane==d

  float acc = 0.f, dacc = 0.f;
  for (unsigned r = wid; r < cnt; r += 4) {
    const unsigned row = bucket[s0 + r];                // wave-uniform broadcast
    const float xv = input[(size_t)row * DIM + lane];   // coalesced 256B
    acc += xv;
    const float er = q - xv;
    dacc = fmaf(er, er, dacc);
    out[OUT_Q + (size_t)row * DIM + lane] = q;
    if (lane == 0) out[OUT_IND + row] = (float)j;
  }
  sacc[wid][lane] = acc;
#pragma unroll
  for (int s = 1; s < 64; s <<= 1) dacc += __shfl_xor(dacc, s, 64);
  if (lane == 0) dred[wid] = dacc;
  __syncthreads();
  if (wid == 0) {
    float s = ((sacc[0][lane] + sacc[1][lane]) + sacc[2][lane]) + sacc[3][lane];
    out[OUT_ES + lane * NEMB + j] = s;                  // embed_sum[d][j]
    if (lane == 0) {
      float dt = ((dred[0] + dred[1]) + dred[2]) + dred[3];
      atomicAdd(out + OUT_DIFF, dt * (1.0f / (float)(NROWS * DIM)));
    }
  }
}

// ---- fallback path (round 4): keys + atomic epilogue ----
__global__ __launch_bounds__(256) void vq_fin(
    const float* __restrict__ input, const float* __restrict__ ws,
    const unsigned long long* __restrict__ keys,
    float* __restrict__ ws_part, float* __restrict__ out, int P) {
  const int tid  = threadIdx.x;
  const int lane = tid & 63;
  const int wid  = tid >> 6;
  const size_t rowBase = (size_t)blockIdx.x * 64;
  float* es = (P > 0) ? (ws_part + (size_t)(blockIdx.x % P) * (NEMB * DIM))
                      : (out + OUT_ES);
  float diffacc = 0.f;
#pragma unroll 1
  for (int r = 0; r < 16; ++r) {
    const int rl = wid * 16 + r;
    const size_t row = rowBase + rl;
    const int J = (int)(keys[row] & 0xffffffffULL);
    float xv = input[row * DIM + lane];
    float q  = ws[WS_ET + (size_t)J * DIM + lane];
    out[OUT_Q + row * DIM + lane] = q;
    float er = q - xv;
    diffacc = fmaf(er, er, diffacc);
    atomicAdd(es + lane * NEMB + J, xv);
    if (lane == 0) {
      out[OUT_IND + row] = (float)J;
      atomicAdd(out + OUT_OH + J, 1.0f);
    }
  }
#pragma unroll
  for (int s = 1; s < 64; s <<= 1) diffacc += __shfl_xor(diffacc, s, 64);
  if (lane == 0)
    atomicAdd(out + OUT_DIFF, diffacc * (1.0f / (float)(NROWS * DIM)));
}

__global__ __launch_bounds__(256) void vq_reduce(const float* __restrict__ ws_part,
                                                 float* __restrict__ out, int P) {
  const int e = blockIdx.x * 256 + threadIdx.x;
  if (e < NEMB * DIM) {
    float s = 0.f;
    for (int p = 0; p < P; ++p) s += ws_part[(size_t)p * (NEMB * DIM) + e];
    out[OUT_ES + e] = s;
  }
}

__global__ __launch_bounds__(256) void vq_mono(
    const float* __restrict__ input, const float* __restrict__ embed,
    const float* __restrict__ ws, float* __restrict__ out) {
  const int i = blockIdx.x * 256 + threadIdx.x;
  float x[DIM];
  const float4* xin = reinterpret_cast<const float4*>(input + (size_t)i * DIM);
#pragma unroll
  for (int k = 0; k < 16; ++k) {
    float4 v = xin[k];
    x[4 * k + 0] = v.x; x[4 * k + 1] = v.y; x[4 * k + 2] = v.z; x[4 * k + 3] = v.w;
  }
  float xx = 0.f;
#pragma unroll
  for (int d = 0; d < DIM; ++d) xx = fmaf(x[d], x[d], xx);
  float best = 3.4e38f; int bj = 0;
#pragma unroll 1
  for (int jt = 0; jt < NEMB; jt += 8) {
    float acc[8];
#pragma unroll
    for (int u = 0; u < 8; ++u) acc[u] = 0.f;
#pragma unroll
    for (int d = 0; d < DIM; ++d) {
      const float xv = x[d];
#pragma unroll
      for (int u = 0; u < 8; ++u)
        acc[u] = fmaf(xv, embed[d * NEMB + jt + u], acc[u]);
    }
#pragma unroll
    for (int u = 0; u < 8; ++u) {
      float dist = (xx - 2.0f * acc[u]) + ws[WS_EN + jt + u];
      if (dist < best) { best = dist; bj = jt + u; }
    }
  }
  out[OUT_IND + i] = (float)bj;
  const float4* qr = reinterpret_cast<const float4*>(ws + WS_ET + (size_t)bj * DIM);
  float4* qo = reinterpret_cast<float4*>(out + (size_t)i * DIM);
  float dsum = 0.f;
#pragma unroll
  for (int k = 0; k < 16; ++k) {
    float4 q = qr[k];
    float e0 = q.x - x[4 * k + 0]; dsum = fmaf(e0, e0, dsum);
    float e1 = q.y - x[4 * k + 1]; dsum = fmaf(e1, e1, dsum);
    float e2 = q.z - x[4 * k + 2]; dsum = fmaf(e2, e2, dsum);
    float e3 = q.w - x[4 * k + 3]; dsum = fmaf(e3, e3, dsum);
    qo[k] = q;
  }
  __shared__ float red[256];
  red[threadIdx.x] = dsum;
  __syncthreads();
#pragma unroll
  for (int s = 128; s > 0; s >>= 1) {
    if (threadIdx.x < s) red[threadIdx.x] += red[threadIdx.x + s];
    __syncthreads();
  }
  if (threadIdx.x == 0)
    atomicAdd(out + OUT_DIFF, red[0] * (1.0f / (float)(NROWS * DIM)));
  atomicAdd(out + OUT_OH + bj, 1.0f);
#pragma unroll
  for (int d = 0; d < DIM; ++d) atomicAdd(out + OUT_ES + d * NEMB + bj, x[d]);
}

extern "C" void kernel_launch(void* const* d_in, const int* in_sizes, int n_in,
                              void* d_out, int out_size, void* d_ws, size_t ws_size,
                              hipStream_t stream) {
  const float* input = (const float*)d_in[0];
  const float* embed = (const float*)d_in[1];
  float* out = (float*)d_out;
  float* ws  = (float*)d_ws;

  long ws_floats = (long)(ws_size / 4);

  if (ws_floats >= WS_NEED) {
    // sort path: no per-row atomics
    unsigned long long* keys = reinterpret_cast<unsigned long long*>(ws + WS_KEY);
    unsigned* hist   = reinterpret_cast<unsigned*>(ws + WS_HIST);
    unsigned* startp = reinterpret_cast<unsigned*>(ws + WS_START);
    unsigned* curs   = reinterpret_cast<unsigned*>(ws + WS_CURS);
    unsigned* bucket = reinterpret_cast<unsigned*>(ws + WS_BUCKET);
    vq_prep<<<256, 256, 0, stream>>>(embed, ws, out, 0, 2);
    dim3 gdist(NROWS / 256, NCHUNK);
    vq_dist<<<gdist, 256, 0, stream>>>(input, embed, ws, keys);
    vq_hist<<<128, 256, 0, stream>>>(keys, hist);
    vq_scan<<<1, 512, 0, stream>>>(hist, startp, curs, out);
    vq_scatter<<<NROWS / 256, 256, 0, stream>>>(keys, curs, bucket);
    vq_finsum<<<NEMB, 256, 0, stream>>>(input, ws, startp, hist, bucket, out);
  } else if (ws_floats >= WS_PART) {
    long p = (ws_floats - WS_PART) / (NEMB * DIM);
    int P = (int)(p > 32 ? 32 : p);
    unsigned long long* keys = reinterpret_cast<unsigned long long*>(ws + WS_KEY);
    float* ws_part = ws + WS_PART;
    vq_prep<<<256, 256, 0, stream>>>(embed, ws, out, P, 1);
    dim3 gdist(NROWS / 256, NCHUNK);
    vq_dist<<<gdist, 256, 0, stream>>>(input, embed, ws, keys);
    vq_fin<<<NROWS / 64, 256, 0, stream>>>(input, ws, keys, ws_part, out, P);
    if (P > 0) vq_reduce<<<(NEMB * DIM + 255) / 256, 256, 0, stream>>>(ws_part, out, P);
  } else {
    vq_prep<<<256, 256, 0, stream>>>(embed, ws, out, 0, 0);
    vq_mono<<<NROWS / 256, 256, 0, stream>>>(input, embed, ws, out);
  }
}

// Round 6
// 315.126 us; speedup vs baseline: 3.5372x; 3.5372x over previous
//
#include <hip/hip_runtime.h>
#include <hip/hip_bf16.h>

// ---- problem geometry ----
#define NROWS   131072          // 32*4096
#define DIM     64
#define NEMB    512
// output offsets (floats)
#define OUT_Q     0
#define OUT_DIFF  8388608
#define OUT_IND   8388609
#define OUT_OH    8519681      // 8388609 + 131072
#define OUT_ES    8520193      // OUT_OH + 512
// ws layout (floats)
#define WS_EN     0
#define WS_ET     512           // embedT [512][64]
#define WS_KEY    33280         // u64 keys [131072], 8B-aligned
#define WS_HIST   295424        // u32[512]
#define WS_START  295936        // u32[512]
#define WS_CURS   296448        // u32[512]
#define WS_BUCKET 296960        // u32[131072]
#define WS_ACC    428032        // f32[512][64]  embed_sum accum ([j][d])
#define WS_DPART  460800        // f32[8192]     per-block diff partials
#define WS_NEED   468992        // floats for the sort path
#define WS_PART   295424        // fallback: P partial embed_sum copies
#define NCHUNK    4
#define CODES_PER_CHUNK 128
#define NSPLIT    16

__global__ __launch_bounds__(256) void vq_prep(const float* __restrict__ embed,
                                               float* __restrict__ ws,
                                               float* __restrict__ out,
                                               int P, int mode) {  // 2=sort,1=keys+part,0=mono
  const int tid = blockIdx.x * 256 + threadIdx.x;
  const int nth = gridDim.x * 256;
  for (int e = tid; e < NEMB * DIM; e += nth) {          // embedT[j][d]
    int j = e >> 6, d = e & 63;
    ws[WS_ET + e] = embed[d * NEMB + j];
  }
  for (int j = tid; j < NEMB; j += nth) {                // en[j]
    float s = 0.f;
    for (int d = 0; d < DIM; ++d) {
      float v = embed[d * NEMB + j];
      s = fmaf(v, v, s);
    }
    ws[WS_EN + j] = s;
  }
  if (mode >= 1) {
    unsigned long long* keys = reinterpret_cast<unsigned long long*>(ws + WS_KEY);
    for (int r = tid; r < NROWS; r += nth) keys[r] = ~0ULL;
  }
  if (mode == 2) {
    unsigned* hist = reinterpret_cast<unsigned*>(ws + WS_HIST);
    for (int k = tid; k < NEMB; k += nth) hist[k] = 0u;
    for (int e = tid; e < NEMB * DIM; e += nth) ws[WS_ACC + e] = 0.f;
  } else {
    if (tid == 0) out[OUT_DIFF] = 0.f;
    for (int e = tid; e < NEMB + NEMB * DIM; e += nth) out[OUT_OH + e] = 0.f;
    for (long e = tid; e < (long)P * (NEMB * DIM); e += nth) ws[WS_PART + e] = 0.f;
  }
}

// Distance + per-chunk argmin (proven: rounds 4/5).
__global__ __launch_bounds__(256, 4) void vq_dist(
    const float* __restrict__ input, const float* __restrict__ embed,
    const float* __restrict__ ws, unsigned long long* __restrict__ keys) {
  const int i = blockIdx.x * 256 + threadIdx.x;
  const int jbase = blockIdx.y * CODES_PER_CHUNK;

  float x[DIM];
  const float4* xin = reinterpret_cast<const float4*>(input + (size_t)i * DIM);
#pragma unroll
  for (int k = 0; k < 16; ++k) {
    float4 v = xin[k];
    x[4 * k + 0] = v.x; x[4 * k + 1] = v.y; x[4 * k + 2] = v.z; x[4 * k + 3] = v.w;
  }
  float xx = 0.f;
#pragma unroll
  for (int d = 0; d < DIM; ++d) xx = fmaf(x[d], x[d], xx);

  float best = 3.4e38f;
  int   bj   = jbase;
#pragma unroll 1
  for (int jt2 = 0; jt2 < CODES_PER_CHUNK; jt2 += 8) {
    const int jt = jbase + jt2;
    float acc[8];
#pragma unroll
    for (int u = 0; u < 8; ++u) acc[u] = 0.f;
#pragma unroll
    for (int d = 0; d < DIM; ++d) {
      const float xv = x[d];
#pragma unroll
      for (int u = 0; u < 8; ++u)
        acc[u] = fmaf(xv, embed[d * NEMB + jt + u], acc[u]);
    }
#pragma unroll
    for (int u = 0; u < 8; ++u) {
      float dist = (xx - 2.0f * acc[u]) + ws[WS_EN + jt + u];
      if (dist < best) { best = dist; bj = jt + u; }
    }
  }
  const unsigned long long key =
      ((unsigned long long)__float_as_uint(fmaxf(best, 0.0f)) << 32) |
      (unsigned long long)(unsigned)bj;
  atomicMin(keys + i, key);
}

// ---- sort path ----
__global__ __launch_bounds__(256) void vq_hist(
    const unsigned long long* __restrict__ keys, unsigned* __restrict__ hist) {
  __shared__ unsigned lh[NEMB];
  const int tid = threadIdx.x;
  for (int k = tid; k < NEMB; k += 256) lh[k] = 0u;
  __syncthreads();
  for (int i = blockIdx.x * 256 + tid; i < NROWS; i += gridDim.x * 256)
    atomicAdd(&lh[(unsigned)(keys[i] & 0xffffffffULL)], 1u);
  __syncthreads();
  for (int k = tid; k < NEMB; k += 256)
    if (lh[k]) atomicAdd(hist + k, lh[k]);
}

__global__ __launch_bounds__(512) void vq_scan(
    const unsigned* __restrict__ hist, unsigned* __restrict__ start,
    unsigned* __restrict__ curs, float* __restrict__ out) {
  __shared__ unsigned lsum[8];
  const int tid = threadIdx.x, lane = tid & 63, wid = tid >> 6;
  unsigned h = hist[tid];
  unsigned v = h;
#pragma unroll
  for (int s = 1; s < 64; s <<= 1) {
    unsigned t = (unsigned)__shfl_up((int)v, s, 64);
    if (lane >= s) v += t;
  }
  if (lane == 63) lsum[wid] = v;
  __syncthreads();
  if (tid == 0) {
    unsigned run = 0;
#pragma unroll
    for (int w = 0; w < 8; ++w) { unsigned t = lsum[w]; lsum[w] = run; run += t; }
  }
  __syncthreads();
  const unsigned excl = v - h + lsum[wid];
  start[tid] = excl;
  curs[tid]  = excl;
  out[OUT_OH + tid] = (float)h;
}

__global__ __launch_bounds__(256) void vq_scatter(
    const unsigned long long* __restrict__ keys, unsigned* __restrict__ curs,
    unsigned* __restrict__ bucket) {
  const int i = blockIdx.x * 256 + threadIdx.x;
  const unsigned J = (unsigned)(keys[i] & 0xffffffffULL);
  const unsigned pos = atomicAdd(curs + J, 1u);
  bucket[pos] = (unsigned)i;
}

// Split segmented reduction: grid (NSPLIT, NEMB), 256 thr = 4 waves.
// Block (s, j) handles slice s of code j's bucket: sums x, writes quantize+ind,
// accumulates embed_sum into ws_acc[j][d] (contiguous atomics), diff -> dpart.
__global__ __launch_bounds__(256) void vq_finsum(
    const float* __restrict__ input, const float* __restrict__ ws,
    const unsigned* __restrict__ start, const unsigned* __restrict__ hist,
    const unsigned* __restrict__ bucket, float* __restrict__ ws_acc,
    float* __restrict__ dpart, float* __restrict__ out) {
  __shared__ float sacc[4][64];
  __shared__ float dred[4];
  const int s    = blockIdx.x;
  const int j    = blockIdx.y;
  const int tid  = threadIdx.x;
  const int lane = tid & 63;
  const int wid  = tid >> 6;
  const unsigned s0    = start[j];
  const unsigned cnt   = hist[j];
  const unsigned chunk = (cnt + NSPLIT - 1) / NSPLIT;
  const unsigned r0    = s * chunk;
  const unsigned r1    = (r0 + chunk < cnt) ? (r0 + chunk) : cnt;
  const float q = ws[WS_ET + (size_t)j * DIM + lane];   // codebook row, lane==d

  float acc = 0.f, dacc = 0.f;
  for (unsigned r = r0 + wid; r < r1; r += 4) {
    const unsigned row = bucket[s0 + r];                // wave-uniform -> s_load
    const float xv = input[(size_t)row * DIM + lane];   // coalesced 256B
    acc += xv;
    const float er = q - xv;
    dacc = fmaf(er, er, dacc);
    out[OUT_Q + (size_t)row * DIM + lane] = q;
    if (lane == 0) out[OUT_IND + row] = (float)j;
  }
  sacc[wid][lane] = acc;
#pragma unroll
  for (int t = 1; t < 64; t <<= 1) dacc += __shfl_xor(dacc, t, 64);
  if (lane == 0) dred[wid] = dacc;
  __syncthreads();
  if (wid == 0) {
    if (r0 < r1) {
      float sm = ((sacc[0][lane] + sacc[1][lane]) + sacc[2][lane]) + sacc[3][lane];
      atomicAdd(ws_acc + (size_t)j * DIM + lane, sm);   // contiguous 64 floats
    }
    if (lane == 0)
      dpart[j * NSPLIT + s] = ((dred[0] + dred[1]) + dred[2]) + dred[3];
  }
}

// Transpose acc -> out[ES] ([d][j]); block 0 also reduces diff (deterministic).
__global__ __launch_bounds__(256) void vq_es(
    const float* __restrict__ ws_acc, const float* __restrict__ dpart,
    float* __restrict__ out) {
  const int e = blockIdx.x * 256 + threadIdx.x;
  const int d = e >> 9, j = e & 511;
  out[OUT_ES + e] = ws_acc[(size_t)j * DIM + d];        // write coalesced
  if (blockIdx.x == 0) {
    __shared__ float red[256];
    const int tid = threadIdx.x;
    float sum = 0.f;
    for (int k = tid; k < NEMB * NSPLIT; k += 256) sum += dpart[k];
    red[tid] = sum;
    __syncthreads();
#pragma unroll
    for (int t = 128; t > 0; t >>= 1) {
      if (tid < t) red[tid] += red[tid + t];
      __syncthreads();
    }
    if (tid == 0) out[OUT_DIFF] = red[0] * (1.0f / (float)(NROWS * DIM));
  }
}

// ---- fallback path (round 4): keys + atomic epilogue ----
__global__ __launch_bounds__(256) void vq_fin(
    const float* __restrict__ input, const float* __restrict__ ws,
    const unsigned long long* __restrict__ keys,
    float* __restrict__ ws_part, float* __restrict__ out, int P) {
  const int tid  = threadIdx.x;
  const int lane = tid & 63;
  const int wid  = tid >> 6;
  const size_t rowBase = (size_t)blockIdx.x * 64;
  float* es = (P > 0) ? (ws_part + (size_t)(blockIdx.x % P) * (NEMB * DIM))
                      : (out + OUT_ES);
  float diffacc = 0.f;
#pragma unroll 1
  for (int r = 0; r < 16; ++r) {
    const int rl = wid * 16 + r;
    const size_t row = rowBase + rl;
    const int J = (int)(keys[row] & 0xffffffffULL);
    float xv = input[row * DIM + lane];
    float q  = ws[WS_ET + (size_t)J * DIM + lane];
    out[OUT_Q + row * DIM + lane] = q;
    float er = q - xv;
    diffacc = fmaf(er, er, diffacc);
    atomicAdd(es + lane * NEMB + J, xv);
    if (lane == 0) {
      out[OUT_IND + row] = (float)J;
      atomicAdd(out + OUT_OH + J, 1.0f);
    }
  }
#pragma unroll
  for (int s = 1; s < 64; s <<= 1) diffacc += __shfl_xor(diffacc, s, 64);
  if (lane == 0)
    atomicAdd(out + OUT_DIFF, diffacc * (1.0f / (float)(NROWS * DIM)));
}

__global__ __launch_bounds__(256) void vq_reduce(const float* __restrict__ ws_part,
                                                 float* __restrict__ out, int P) {
  const int e = blockIdx.x * 256 + threadIdx.x;
  if (e < NEMB * DIM) {
    float s = 0.f;
    for (int p = 0; p < P; ++p) s += ws_part[(size_t)p * (NEMB * DIM) + e];
    out[OUT_ES + e] = s;
  }
}

__global__ __launch_bounds__(256) void vq_mono(
    const float* __restrict__ input, const float* __restrict__ embed,
    const float* __restrict__ ws, float* __restrict__ out) {
  const int i = blockIdx.x * 256 + threadIdx.x;
  float x[DIM];
  const float4* xin = reinterpret_cast<const float4*>(input + (size_t)i * DIM);
#pragma unroll
  for (int k = 0; k < 16; ++k) {
    float4 v = xin[k];
    x[4 * k + 0] = v.x; x[4 * k + 1] = v.y; x[4 * k + 2] = v.z; x[4 * k + 3] = v.w;
  }
  float xx = 0.f;
#pragma unroll
  for (int d = 0; d < DIM; ++d) xx = fmaf(x[d], x[d], xx);
  float best = 3.4e38f; int bj = 0;
#pragma unroll 1
  for (int jt = 0; jt < NEMB; jt += 8) {
    float acc[8];
#pragma unroll
    for (int u = 0; u < 8; ++u) acc[u] = 0.f;
#pragma unroll
    for (int d = 0; d < DIM; ++d) {
      const float xv = x[d];
#pragma unroll
      for (int u = 0; u < 8; ++u)
        acc[u] = fmaf(xv, embed[d * NEMB + jt + u], acc[u]);
    }
#pragma unroll
    for (int u = 0; u < 8; ++u) {
      float dist = (xx - 2.0f * acc[u]) + ws[WS_EN + jt + u];
      if (dist < best) { best = dist; bj = jt + u; }
    }
  }
  out[OUT_IND + i] = (float)bj;
  const float4* qr = reinterpret_cast<const float4*>(ws + WS_ET + (size_t)bj * DIM);
  float4* qo = reinterpret_cast<float4*>(out + (size_t)i * DIM);
  float dsum = 0.f;
#pragma unroll
  for (int k = 0; k < 16; ++k) {
    float4 q = qr[k];
    float e0 = q.x - x[4 * k + 0]; dsum = fmaf(e0, e0, dsum);
    float e1 = q.y - x[4 * k + 1]; dsum = fmaf(e1, e1, dsum);
    float e2 = q.z - x[4 * k + 2]; dsum = fmaf(e2, e2, dsum);
    float e3 = q.w - x[4 * k + 3]; dsum = fmaf(e3, e3, dsum);
    qo[k] = q;
  }
  __shared__ float red[256];
  red[threadIdx.x] = dsum;
  __syncthreads();
#pragma unroll
  for (int s = 128; s > 0; s >>= 1) {
    if (threadIdx.x < s) red[threadIdx.x] += red[threadIdx.x + s];
    __syncthreads();
  }
  if (threadIdx.x == 0)
    atomicAdd(out + OUT_DIFF, red[0] * (1.0f / (float)(NROWS * DIM)));
  atomicAdd(out + OUT_OH + bj, 1.0f);
#pragma unroll
  for (int d = 0; d < DIM; ++d) atomicAdd(out + OUT_ES + d * NEMB + bj, x[d]);
}

extern "C" void kernel_launch(void* const* d_in, const int* in_sizes, int n_in,
                              void* d_out, int out_size, void* d_ws, size_t ws_size,
                              hipStream_t stream) {
  const float* input = (const float*)d_in[0];
  const float* embed = (const float*)d_in[1];
  float* out = (float*)d_out;
  float* ws  = (float*)d_ws;

  long ws_floats = (long)(ws_size / 4);

  if (ws_floats >= WS_NEED) {
    unsigned long long* keys = reinterpret_cast<unsigned long long*>(ws + WS_KEY);
    unsigned* hist   = reinterpret_cast<unsigned*>(ws + WS_HIST);
    unsigned* startp = reinterpret_cast<unsigned*>(ws + WS_START);
    unsigned* curs   = reinterpret_cast<unsigned*>(ws + WS_CURS);
    unsigned* bucket = reinterpret_cast<unsigned*>(ws + WS_BUCKET);
    float*    ws_acc = ws + WS_ACC;
    float*    dpart  = ws + WS_DPART;
    vq_prep<<<256, 256, 0, stream>>>(embed, ws, out, 0, 2);
    dim3 gdist(NROWS / 256, NCHUNK);
    vq_dist<<<gdist, 256, 0, stream>>>(input, embed, ws, keys);
    vq_hist<<<128, 256, 0, stream>>>(keys, hist);
    vq_scan<<<1, 512, 0, stream>>>(hist, startp, curs, out);
    vq_scatter<<<NROWS / 256, 256, 0, stream>>>(keys, curs, bucket);
    dim3 gfin(NSPLIT, NEMB);
    vq_finsum<<<gfin, 256, 0, stream>>>(input, ws, startp, hist, bucket,
                                        ws_acc, dpart, out);
    vq_es<<<NEMB * DIM / 256, 256, 0, stream>>>(ws_acc, dpart, out);
  } else if (ws_floats >= WS_PART) {
    long p = (ws_floats - WS_PART) / (NEMB * DIM);
    int P = (int)(p > 32 ? 32 : p);
    unsigned long long* keys = reinterpret_cast<unsigned long long*>(ws + WS_KEY);
    float* ws_part = ws + WS_PART;
    vq_prep<<<256, 256, 0, stream>>>(embed, ws, out, P, 1);
    dim3 gdist(NROWS / 256, NCHUNK);
    vq_dist<<<gdist, 256, 0, stream>>>(input, embed, ws, keys);
    vq_fin<<<NROWS / 64, 256, 0, stream>>>(input, ws, keys, ws_part, out, P);
    if (P > 0) vq_reduce<<<(NEMB * DIM + 255) / 256, 256, 0, stream>>>(ws_part, out, P);
  } else {
    vq_prep<<<256, 256, 0, stream>>>(embed, ws, out, 0, 0);
    vq_mono<<<NROWS / 256, 256, 0, stream>>>(input, embed, ws, out);
  }
}

// Round 7
// 312.196 us; speedup vs baseline: 3.5703x; 1.0094x over previous
//
#include <hip/hip_runtime.h>
#include <hip/hip_bf16.h>

// ---- problem geometry ----
#define NROWS   131072          // 32*4096
#define DIM     64
#define NEMB    512
// output offsets (floats)
#define OUT_Q     0
#define OUT_DIFF  8388608
#define OUT_IND   8388609
#define OUT_OH    8519681      // 8388609 + 131072
#define OUT_ES    8520193      // OUT_OH + 512
// ws layout (floats)
#define WS_EN     0
#define WS_ET     512           // embedT [512][64]
#define WS_KEY    33280         // u64 keys [131072], 8B-aligned
#define WS_HIST   295424        // u32[512]
#define WS_START  295936        // u32[512]
#define WS_CURS   296448        // u32[512]
#define WS_BUCKET 296960        // u32[131072]
#define WS_ACC    428032        // f32[512][64]  embed_sum accum ([j][d])
#define WS_DPART  460800        // f32[2048]     per-wave diff partials
#define WS_NEED   468992        // floats for the sort path
#define WS_PART   295424        // fallback: P partial embed_sum copies
#define NCHUNK    4
#define CODES_PER_CHUNK 128
#define NWAVE_FIN 2048          // 131072 positions / 64 per wave

__global__ __launch_bounds__(256) void vq_prep(const float* __restrict__ embed,
                                               float* __restrict__ ws,
                                               float* __restrict__ out,
                                               int P, int mode) {  // 2=sort,1=keys+part,0=mono
  const int tid = blockIdx.x * 256 + threadIdx.x;
  const int nth = gridDim.x * 256;
  for (int e = tid; e < NEMB * DIM; e += nth) {          // embedT[j][d]
    int j = e >> 6, d = e & 63;
    ws[WS_ET + e] = embed[d * NEMB + j];
  }
  for (int j = tid; j < NEMB; j += nth) {                // en[j]
    float s = 0.f;
    for (int d = 0; d < DIM; ++d) {
      float v = embed[d * NEMB + j];
      s = fmaf(v, v, s);
    }
    ws[WS_EN + j] = s;
  }
  if (mode >= 1) {
    unsigned long long* keys = reinterpret_cast<unsigned long long*>(ws + WS_KEY);
    for (int r = tid; r < NROWS; r += nth) keys[r] = ~0ULL;
  }
  if (mode == 2) {
    unsigned* hist = reinterpret_cast<unsigned*>(ws + WS_HIST);
    for (int k = tid; k < NEMB; k += nth) hist[k] = 0u;
    for (int e = tid; e < NEMB * DIM; e += nth) ws[WS_ACC + e] = 0.f;
  } else {
    if (tid == 0) out[OUT_DIFF] = 0.f;
    for (int e = tid; e < NEMB + NEMB * DIM; e += nth) out[OUT_OH + e] = 0.f;
    for (long e = tid; e < (long)P * (NEMB * DIM); e += nth) ws[WS_PART + e] = 0.f;
  }
}

// Distance + per-chunk argmin. 2 rows/thread: one scalar embed stream feeds
// 2x the FMAs (halves s_load stall and per-CU embed re-fetch).
__global__ __launch_bounds__(256, 3) void vq_dist(
    const float* __restrict__ input, const float* __restrict__ embed,
    const float* __restrict__ ws, unsigned long long* __restrict__ keys) {
  const int ia = blockIdx.x * 256 + threadIdx.x;      // row a
  const int ib = ia + (NROWS / 2);                    // row b
  const int jbase = blockIdx.y * CODES_PER_CHUNK;

  float xa[DIM], xb[DIM];
  const float4* xin_a = reinterpret_cast<const float4*>(input + (size_t)ia * DIM);
  const float4* xin_b = reinterpret_cast<const float4*>(input + (size_t)ib * DIM);
#pragma unroll
  for (int k = 0; k < 16; ++k) {
    float4 va = xin_a[k];
    xa[4 * k + 0] = va.x; xa[4 * k + 1] = va.y; xa[4 * k + 2] = va.z; xa[4 * k + 3] = va.w;
    float4 vb = xin_b[k];
    xb[4 * k + 0] = vb.x; xb[4 * k + 1] = vb.y; xb[4 * k + 2] = vb.z; xb[4 * k + 3] = vb.w;
  }
  float xxa = 0.f, xxb = 0.f;
#pragma unroll
  for (int d = 0; d < DIM; ++d) { xxa = fmaf(xa[d], xa[d], xxa); xxb = fmaf(xb[d], xb[d], xxb); }

  float bestA = 3.4e38f, bestB = 3.4e38f;
  int   bjA = jbase, bjB = jbase;
#pragma unroll 1
  for (int jt2 = 0; jt2 < CODES_PER_CHUNK; jt2 += 8) {
    const int jt = jbase + jt2;
    float accA[8], accB[8];
#pragma unroll
    for (int u = 0; u < 8; ++u) { accA[u] = 0.f; accB[u] = 0.f; }
#pragma unroll
    for (int d = 0; d < DIM; ++d) {
      const float xva = xa[d], xvb = xb[d];
#pragma unroll
      for (int u = 0; u < 8; ++u) {
        const float ev = embed[d * NEMB + jt + u];       // wave-uniform -> s_load
        accA[u] = fmaf(xva, ev, accA[u]);
        accB[u] = fmaf(xvb, ev, accB[u]);
      }
    }
#pragma unroll
    for (int u = 0; u < 8; ++u) {
      const float en = ws[WS_EN + jt + u];
      float Da = (xxa - 2.0f * accA[u]) + en;             // np expr order
      float Db = (xxb - 2.0f * accB[u]) + en;
      if (Da < bestA) { bestA = Da; bjA = jt + u; }
      if (Db < bestB) { bestB = Db; bjB = jt + u; }
    }
  }
  const unsigned long long keyA =
      ((unsigned long long)__float_as_uint(fmaxf(bestA, 0.0f)) << 32) |
      (unsigned long long)(unsigned)bjA;
  const unsigned long long keyB =
      ((unsigned long long)__float_as_uint(fmaxf(bestB, 0.0f)) << 32) |
      (unsigned long long)(unsigned)bjB;
  atomicMin(keys + ia, keyA);
  atomicMin(keys + ib, keyB);
}

// ---- sort path ----
__global__ __launch_bounds__(256) void vq_hist(
    const unsigned long long* __restrict__ keys, unsigned* __restrict__ hist) {
  __shared__ unsigned lh[NEMB];
  const int tid = threadIdx.x;
  for (int k = tid; k < NEMB; k += 256) lh[k] = 0u;
  __syncthreads();
  for (int i = blockIdx.x * 256 + tid; i < NROWS; i += gridDim.x * 256)
    atomicAdd(&lh[(unsigned)(keys[i] & 0xffffffffULL)], 1u);
  __syncthreads();
  for (int k = tid; k < NEMB; k += 256)
    if (lh[k]) atomicAdd(hist + k, lh[k]);
}

__global__ __launch_bounds__(512) void vq_scan(
    const unsigned* __restrict__ hist, unsigned* __restrict__ start,
    unsigned* __restrict__ curs, float* __restrict__ out) {
  __shared__ unsigned lsum[8];
  const int tid = threadIdx.x, lane = tid & 63, wid = tid >> 6;
  unsigned h = hist[tid];
  unsigned v = h;
#pragma unroll
  for (int s = 1; s < 64; s <<= 1) {
    unsigned t = (unsigned)__shfl_up((int)v, s, 64);
    if (lane >= s) v += t;
  }
  if (lane == 63) lsum[wid] = v;
  __syncthreads();
  if (tid == 0) {
    unsigned run = 0;
#pragma unroll
    for (int w = 0; w < 8; ++w) { unsigned t = lsum[w]; lsum[w] = run; run += t; }
  }
  __syncthreads();
  const unsigned excl = v - h + lsum[wid];
  start[tid] = excl;
  curs[tid]  = excl;
  out[OUT_OH + tid] = (float)h;
}

__global__ __launch_bounds__(256) void vq_scatter(
    const unsigned long long* __restrict__ keys, unsigned* __restrict__ curs,
    unsigned* __restrict__ bucket) {
  const int i = blockIdx.x * 256 + threadIdx.x;
  const unsigned J = (unsigned)(keys[i] & 0xffffffffULL);
  const unsigned pos = atomicAdd(curs + J, 1u);
  bucket[pos] = (unsigned)i;
}

// Position-balanced segmented sum: each wave owns exactly 64 bucket positions.
// Sorted order => j non-decreasing per wave => register-held running sum,
// flushed with 64 contiguous atomics only at j boundaries.
__global__ __launch_bounds__(256) void vq_finsum2(
    const float* __restrict__ input, const float* __restrict__ ws,
    const unsigned long long* __restrict__ keys,
    const unsigned* __restrict__ bucket, float* __restrict__ ws_acc,
    float* __restrict__ dpart, float* __restrict__ out) {
  const int tid  = threadIdx.x;
  const int lane = tid & 63;
  const int wid  = tid >> 6;
  const int waveIdx = blockIdx.x * 4 + wid;           // 0..2047
  const unsigned posBase = (unsigned)waveIdx * 64;

  float sum = 0.f, dacc = 0.f, q = 0.f;
  int jcur = -1;
  unsigned row = bucket[posBase];                      // uniform -> s_load
  int j = (int)(keys[row] & 0xffffffffULL);
#pragma unroll 1
  for (int p = 0; p < 64; ++p) {
    // prefetch next position's row/key while processing this one
    unsigned rowN = 0; int jN = 0;
    if (p < 63) {
      rowN = bucket[posBase + p + 1];
      jN = (int)(keys[rowN] & 0xffffffffULL);
    }
    if (j != jcur) {                                   // wave-uniform branch
      if (jcur >= 0) atomicAdd(ws_acc + (size_t)jcur * DIM + lane, sum);
      sum = 0.f; jcur = j;
      q = ws[WS_ET + (size_t)j * DIM + lane];          // coalesced 256B
    }
    const float xv = input[(size_t)row * DIM + lane];  // coalesced 256B
    sum += xv;
    const float er = q - xv;
    dacc = fmaf(er, er, dacc);
    out[OUT_Q + (size_t)row * DIM + lane] = q;
    if (lane == 0) out[OUT_IND + row] = (float)j;
    row = rowN; j = jN;
  }
  atomicAdd(ws_acc + (size_t)jcur * DIM + lane, sum);
#pragma unroll
  for (int s = 1; s < 64; s <<= 1) dacc += __shfl_xor(dacc, s, 64);
  if (lane == 0) dpart[waveIdx] = dacc;
}

// Transpose acc -> out[ES] ([d][j]); block 0 reduces diff (deterministic).
__global__ __launch_bounds__(256) void vq_es(
    const float* __restrict__ ws_acc, const float* __restrict__ dpart,
    float* __restrict__ out, int ndpart) {
  const int e = blockIdx.x * 256 + threadIdx.x;
  const int d = e >> 9, j = e & 511;
  out[OUT_ES + e] = ws_acc[(size_t)j * DIM + d];        // write coalesced
  if (blockIdx.x == 0) {
    __shared__ float red[256];
    const int tid = threadIdx.x;
    float sum = 0.f;
    for (int k = tid; k < ndpart; k += 256) sum += dpart[k];
    red[tid] = sum;
    __syncthreads();
#pragma unroll
    for (int t = 128; t > 0; t >>= 1) {
      if (tid < t) red[tid] += red[tid + t];
      __syncthreads();
    }
    if (tid == 0) out[OUT_DIFF] = red[0] * (1.0f / (float)(NROWS * DIM));
  }
}

// ---- fallback path (round 4): keys + atomic epilogue ----
__global__ __launch_bounds__(256) void vq_fin(
    const float* __restrict__ input, const float* __restrict__ ws,
    const unsigned long long* __restrict__ keys,
    float* __restrict__ ws_part, float* __restrict__ out, int P) {
  const int tid  = threadIdx.x;
  const int lane = tid & 63;
  const int wid  = tid >> 6;
  const size_t rowBase = (size_t)blockIdx.x * 64;
  float* es = (P > 0) ? (ws_part + (size_t)(blockIdx.x % P) * (NEMB * DIM))
                      : (out + OUT_ES);
  float diffacc = 0.f;
#pragma unroll 1
  for (int r = 0; r < 16; ++r) {
    const int rl = wid * 16 + r;
    const size_t row = rowBase + rl;
    const int J = (int)(keys[row] & 0xffffffffULL);
    float xv = input[row * DIM + lane];
    float q  = ws[WS_ET + (size_t)J * DIM + lane];
    out[OUT_Q + row * DIM + lane] = q;
    float er = q - xv;
    diffacc = fmaf(er, er, diffacc);
    atomicAdd(es + lane * NEMB + J, xv);
    if (lane == 0) {
      out[OUT_IND + row] = (float)J;
      atomicAdd(out + OUT_OH + J, 1.0f);
    }
  }
#pragma unroll
  for (int s = 1; s < 64; s <<= 1) diffacc += __shfl_xor(diffacc, s, 64);
  if (lane == 0)
    atomicAdd(out + OUT_DIFF, diffacc * (1.0f / (float)(NROWS * DIM)));
}

__global__ __launch_bounds__(256) void vq_reduce(const float* __restrict__ ws_part,
                                                 float* __restrict__ out, int P) {
  const int e = blockIdx.x * 256 + threadIdx.x;
  if (e < NEMB * DIM) {
    float s = 0.f;
    for (int p = 0; p < P; ++p) s += ws_part[(size_t)p * (NEMB * DIM) + e];
    out[OUT_ES + e] = s;
  }
}

__global__ __launch_bounds__(256) void vq_mono(
    const float* __restrict__ input, const float* __restrict__ embed,
    const float* __restrict__ ws, float* __restrict__ out) {
  const int i = blockIdx.x * 256 + threadIdx.x;
  float x[DIM];
  const float4* xin = reinterpret_cast<const float4*>(input + (size_t)i * DIM);
#pragma unroll
  for (int k = 0; k < 16; ++k) {
    float4 v = xin[k];
    x[4 * k + 0] = v.x; x[4 * k + 1] = v.y; x[4 * k + 2] = v.z; x[4 * k + 3] = v.w;
  }
  float xx = 0.f;
#pragma unroll
  for (int d = 0; d < DIM; ++d) xx = fmaf(x[d], x[d], xx);
  float best = 3.4e38f; int bj = 0;
#pragma unroll 1
  for (int jt = 0; jt < NEMB; jt += 8) {
    float acc[8];
#pragma unroll
    for (int u = 0; u < 8; ++u) acc[u] = 0.f;
#pragma unroll
    for (int d = 0; d < DIM; ++d) {
      const float xv = x[d];
#pragma unroll
      for (int u = 0; u < 8; ++u)
        acc[u] = fmaf(xv, embed[d * NEMB + jt + u], acc[u]);
    }
#pragma unroll
    for (int u = 0; u < 8; ++u) {
      float dist = (xx - 2.0f * acc[u]) + ws[WS_EN + jt + u];
      if (dist < best) { best = dist; bj = jt + u; }
    }
  }
  out[OUT_IND + i] = (float)bj;
  const float4* qr = reinterpret_cast<const float4*>(ws + WS_ET + (size_t)bj * DIM);
  float4* qo = reinterpret_cast<float4*>(out + (size_t)i * DIM);
  float dsum = 0.f;
#pragma unroll
  for (int k = 0; k < 16; ++k) {
    float4 q = qr[k];
    float e0 = q.x - x[4 * k + 0]; dsum = fmaf(e0, e0, dsum);
    float e1 = q.y - x[4 * k + 1]; dsum = fmaf(e1, e1, dsum);
    float e2 = q.z - x[4 * k + 2]; dsum = fmaf(e2, e2, dsum);
    float e3 = q.w - x[4 * k + 3]; dsum = fmaf(e3, e3, dsum);
    qo[k] = q;
  }
  __shared__ float red[256];
  red[threadIdx.x] = dsum;
  __syncthreads();
#pragma unroll
  for (int s = 128; s > 0; s >>= 1) {
    if (threadIdx.x < s) red[threadIdx.x] += red[threadIdx.x + s];
    __syncthreads();
  }
  if (threadIdx.x == 0)
    atomicAdd(out + OUT_DIFF, red[0] * (1.0f / (float)(NROWS * DIM)));
  atomicAdd(out + OUT_OH + bj, 1.0f);
#pragma unroll
  for (int d = 0; d < DIM; ++d) atomicAdd(out + OUT_ES + d * NEMB + bj, x[d]);
}

extern "C" void kernel_launch(void* const* d_in, const int* in_sizes, int n_in,
                              void* d_out, int out_size, void* d_ws, size_t ws_size,
                              hipStream_t stream) {
  const float* input = (const float*)d_in[0];
  const float* embed = (const float*)d_in[1];
  float* out = (float*)d_out;
  float* ws  = (float*)d_ws;

  long ws_floats = (long)(ws_size / 4);

  if (ws_floats >= WS_NEED) {
    unsigned long long* keys = reinterpret_cast<unsigned long long*>(ws + WS_KEY);
    unsigned* hist   = reinterpret_cast<unsigned*>(ws + WS_HIST);
    unsigned* startp = reinterpret_cast<unsigned*>(ws + WS_START);
    unsigned* curs   = reinterpret_cast<unsigned*>(ws + WS_CURS);
    unsigned* bucket = reinterpret_cast<unsigned*>(ws + WS_BUCKET);
    float*    ws_acc = ws + WS_ACC;
    float*    dpart  = ws + WS_DPART;
    vq_prep<<<256, 256, 0, stream>>>(embed, ws, out, 0, 2);
    dim3 gdist(NROWS / 2 / 256, NCHUNK);
    vq_dist<<<gdist, 256, 0, stream>>>(input, embed, ws, keys);
    vq_hist<<<128, 256, 0, stream>>>(keys, hist);
    vq_scan<<<1, 512, 0, stream>>>(hist, startp, curs, out);
    vq_scatter<<<NROWS / 256, 256, 0, stream>>>(keys, curs, bucket);
    vq_finsum2<<<NWAVE_FIN / 4, 256, 0, stream>>>(input, ws, keys, bucket,
                                                  ws_acc, dpart, out);
    vq_es<<<NEMB * DIM / 256, 256, 0, stream>>>(ws_acc, dpart, out, NWAVE_FIN);
  } else if (ws_floats >= WS_PART) {
    long p = (ws_floats - WS_PART) / (NEMB * DIM);
    int P = (int)(p > 32 ? 32 : p);
    unsigned long long* keys = reinterpret_cast<unsigned long long*>(ws + WS_KEY);
    float* ws_part = ws + WS_PART;
    vq_prep<<<256, 256, 0, stream>>>(embed, ws, out, P, 1);
    dim3 gdist(NROWS / 256, NCHUNK);
    // fallback path keeps 1 row/thread kernel shape via vq_mono-style vq_fin
    vq_dist<<<dim3(NROWS / 2 / 256, NCHUNK), 256, 0, stream>>>(input, embed, ws, keys);
    vq_fin<<<NROWS / 64, 256, 0, stream>>>(input, ws, keys, ws_part, out, P);
    if (P > 0) vq_reduce<<<(NEMB * DIM + 255) / 256, 256, 0, stream>>>(ws_part, out, P);
  } else {
    vq_prep<<<256, 256, 0, stream>>>(embed, ws, out, 0, 0);
    vq_mono<<<NROWS / 256, 256, 0, stream>>>(input, embed, ws, out);
  }
}